// Round 3
// baseline (384.064 us; speedup 1.0000x reference)
//
#include <hip/hip_runtime.h>

#define N_NODES 50000
#define N_EDGES 800000
#define IN_C 8
#define OUT_C 16
#define EDGE_F 8
#define HEADS 4
#define HID 64
#define GDIM (HEADS*HID)   // 256
#define FINAL 128
#define NEG_SLOPE 0.2f
#define EB ((N_EDGES+255)/256)      // 3125
#define NBLK 196                    // ceil(N_NODES/256)

__device__ __forceinline__ int clampn(int v) {
    return v < 0 ? 0 : (v >= N_NODES ? N_NODES - 1 : v);
}

// ---------- K_histfold: dst histogram + rank, plus folded attention weights ----------
__global__ __launch_bounds__(256) void k_histfold(
    const int* __restrict__ dst, int* __restrict__ cnt, int* __restrict__ rnk,
    const float* __restrict__ gat_lin,
    const float* __restrict__ att_src_w, const float* __restrict__ att_dst_w,
    float* __restrict__ wsrc, float* __restrict__ wdst)
{
    if (blockIdx.x < EB) {
        int e = blockIdx.x * 256 + threadIdx.x;
        if (e >= N_EDGES) return;
        rnk[e] = atomicAdd(&cnt[clampn(dst[e])], 1);
    } else {
        int t = threadIdx.x;           // t = c*4 + h
        if (t >= 64) return;
        int c = t >> 2, h = t & 3;
        float ws = 0.f, wd = 0.f;
        for (int k = 0; k < HID; k++) {
            float l = gat_lin[c * GDIM + h * HID + k];
            ws += l * att_src_w[h * HID + k];
            wd += l * att_dst_w[h * HID + k];
        }
        wsrc[t] = ws;
        wdst[t] = wd;
    }
}

// ---------- scan pipeline ----------
__global__ __launch_bounds__(256) void k_part(const int* __restrict__ cnt,
                                              int* __restrict__ part)
{
    int i = blockIdx.x * 256 + threadIdx.x;
    int v = (i < N_NODES) ? cnt[i] : 0;
#pragma unroll
    for (int off = 32; off; off >>= 1) v += __shfl_down(v, off);
    __shared__ int ws[4];
    if ((threadIdx.x & 63) == 0) ws[threadIdx.x >> 6] = v;
    __syncthreads();
    if (threadIdx.x == 0) part[blockIdx.x] = ws[0] + ws[1] + ws[2] + ws[3];
}

__global__ __launch_bounds__(256) void k_scan1(const int* __restrict__ part,
                                               int* __restrict__ partscan)
{
    int t = threadIdx.x;
    int v = (t < NBLK) ? part[t] : 0;
    int lane = t & 63, wid = t >> 6;
    int incl = v;
#pragma unroll
    for (int off = 1; off < 64; off <<= 1) {
        int u = __shfl_up(incl, off);
        if (lane >= off) incl += u;
    }
    __shared__ int wsum[4];
    if (lane == 63) wsum[wid] = incl;
    __syncthreads();
    int add = 0;
    for (int w = 0; w < wid; w++) add += wsum[w];
    partscan[t] = incl - v + add;   // exclusive
}

__global__ __launch_bounds__(256) void k_add(const int* __restrict__ cnt,
                                             const int* __restrict__ partscan,
                                             int* __restrict__ offs)
{
    int i = blockIdx.x * 256 + threadIdx.x;
    int v = (i < N_NODES) ? cnt[i] : 0;
    int lane = threadIdx.x & 63, wid = threadIdx.x >> 6;
    int incl = v;
#pragma unroll
    for (int off = 1; off < 64; off <<= 1) {
        int u = __shfl_up(incl, off);
        if (lane >= off) incl += u;
    }
    __shared__ int wsum[4];
    if (lane == 63) wsum[wid] = incl;
    __syncthreads();
    int add = partscan[blockIdx.x];
    for (int w = 0; w < wid; w++) add += wsum[w];
    if (i < N_NODES) offs[i] = incl - v + add;
    if (i == 0) offs[N_NODES] = N_EDGES;
}

// ---------- K_scatter: build CSR src list AND CSR-ordered edge-attr copy ----------
__global__ __launch_bounds__(256) void k_scatter(
    const int* __restrict__ src, const int* __restrict__ dst,
    const int* __restrict__ rnk, const int* __restrict__ offs,
    const float* __restrict__ ea,
    int* __restrict__ src_csr, float* __restrict__ ea_csr)
{
    int e = blockIdx.x * 256 + threadIdx.x;
    if (e >= N_EDGES) return;
    int p = offs[clampn(dst[e])] + rnk[e];
    src_csr[p] = clampn(src[e]);
    const float4* s4 = (const float4*)&ea[(size_t)e * EDGE_F];
    float4* d4 = (float4*)&ea_csr[(size_t)p * EDGE_F];
    d4[0] = s4[0];
    d4[1] = s4[1];
}

// ---------- K2T: wave-per-node T-factorized NNConv, p-parallel epilogue ----------
// ea now CSR-ordered -> sequential streaming reads instead of random 32B gathers.
__global__ __launch_bounds__(256) void k2T_wave(
    const float* __restrict__ x,
    const int* __restrict__ src_csr, const int* __restrict__ offs,
    const float* __restrict__ ea_csr,
    const float* __restrict__ mlp_w, const float* __restrict__ mlp_b,
    const float* __restrict__ ecc_root, const float* __restrict__ ecc_bias,
    const float* __restrict__ wsrc, const float* __restrict__ wdst,
    float* __restrict__ h_tab, float* __restrict__ asrc, float* __restrict__ adst)
{
    __shared__ float smW[64 * 17];   // [jj][o] pitch-17 (bank-friendly)
    __shared__ float smb[128];
    __shared__ float sroot[128];
    __shared__ float sbias[16];
    __shared__ float sws[64], swd[64];
    __shared__ float sT[4][64];
    __shared__ float sxs[4][8];

    int t = threadIdx.x;
    for (int idx = t; idx < 1024; idx += 256)
        smW[(idx >> 4) * 17 + (idx & 15)] = mlp_w[idx];
    if (t < 128) smb[t] = mlp_b[t];
    if (t >= 128 && t < 256) sroot[t - 128] = ecc_root[t - 128];
    if (t < 16) sbias[t] = ecc_bias[t];
    if (t >= 32 && t < 96) sws[t - 32] = wsrc[t - 32];
    if (t >= 96 && t < 160) swd[t - 96] = wdst[t - 96];

    int wid = t >> 6, lane = t & 63;
    int n = blockIdx.x * 4 + wid;   // grid = 12500 exactly
    int f = lane >> 3, i = lane & 7;
    int beg = offs[n], end = offs[n + 1];

    float t0 = 0.f, t1 = 0.f, t2 = 0.f, t3 = 0.f, xs = 0.f;
    int j = beg;
    for (; j + 3 < end; j += 4) {
        int s0 = src_csr[j],     s1 = src_csr[j + 1];
        int s2 = src_csr[j + 2], s3 = src_csr[j + 3];
        float a0 = ea_csr[(size_t)j * EDGE_F + f];
        float a1 = ea_csr[(size_t)(j + 1) * EDGE_F + f];
        float a2 = ea_csr[(size_t)(j + 2) * EDGE_F + f];
        float a3 = ea_csr[(size_t)(j + 3) * EDGE_F + f];
        float x0 = x[s0 * IN_C + i];
        float x1 = x[s1 * IN_C + i];
        float x2 = x[s2 * IN_C + i];
        float x3 = x[s3 * IN_C + i];
        t0 += a0 * x0; t1 += a1 * x1; t2 += a2 * x2; t3 += a3 * x3;
        xs += (x0 + x1) + (x2 + x3);
    }
    for (; j < end; j++) {
        int s = src_csr[j];
        float a = ea_csr[(size_t)j * EDGE_F + f];
        float xv = x[s * IN_C + i];
        t0 += a * xv;
        xs += xv;
    }
    sT[wid][lane] = (t0 + t1) + (t2 + t3);
    if (f == 0) sxs[wid][i] = xs;
    __syncthreads();     // covers LDS preloads + sT/sxs

    // p-parallel 64x16 contraction: lane = p*16 + o, partial over jj=p*16..+15
    int o = lane & 15, p = lane >> 4;
    float v = 0.f;
#pragma unroll
    for (int q2 = 0; q2 < 16; q2++) {
        int jj = p * 16 + q2;
        v += smW[jj * 17 + o] * sT[wid][jj];
    }
    v += __shfl_down(v, 32);
    v += __shfl_down(v, 16);    // lanes<16 hold full sums

    float hv = 0.f;
    if (lane < 16) {
        float vv = v + sbias[o];
#pragma unroll
        for (int ii = 0; ii < IN_C; ii++) {
            vv += smb[ii * 16 + o] * sxs[wid][ii];
            vv += x[n * IN_C + ii] * sroot[ii * 16 + o];
        }
        hv = fmaxf(vv, 0.f);
        h_tab[n * OUT_C + o] = hv;
    }
    // folded attention logits
    float as = 0.f, ad = 0.f;
    int h2 = lane & 3;
#pragma unroll
    for (int c = 0; c < 16; c++) {
        float hc = __shfl(hv, c);
        as += hc * sws[c * 4 + h2];
        ad += hc * swd[c * 4 + h2];
    }
    if (lane < 4) {
        asrc[n * HEADS + lane] = as;
        adst[n * HEADS + lane] = ad;
    }
}

// ---------- K_gatE: wave-per-node U accumulation, normalized in-register ----------
// lane = h*16+c; den is identical across the 16 lanes of a head -> no reduce.
__global__ __launch_bounds__(256) void k_gatE(
    const int* __restrict__ offs, const int* __restrict__ src_csr,
    const float* __restrict__ asrc, const float* __restrict__ adst,
    const float* __restrict__ h_tab, float* __restrict__ U_all)
{
    int t = threadIdx.x;
    int wid = t >> 6, lane = t & 63;
    int n = blockIdx.x * 4 + wid;   // grid = 12500 exactly
    int h = lane >> 4, c = lane & 15;
    float adsth = adst[n * HEADS + h];
    int beg = offs[n], end = offs[n + 1];

    float U = 0.f, den = 0.f;
    int j = beg;
    for (; j + 3 < end; j += 4) {
        int s0 = src_csr[j],     s1 = src_csr[j + 1];
        int s2 = src_csr[j + 2], s3 = src_csr[j + 3];
        float av0 = asrc[s0 * HEADS + h], av1 = asrc[s1 * HEADS + h];
        float av2 = asrc[s2 * HEADS + h], av3 = asrc[s3 * HEADS + h];
        float h0 = h_tab[s0 * OUT_C + c], h1 = h_tab[s1 * OUT_C + c];
        float h2v = h_tab[s2 * OUT_C + c], h3v = h_tab[s3 * OUT_C + c];
        float v0 = av0 + adsth; v0 = v0 > 0.f ? v0 : NEG_SLOPE * v0;
        float v1 = av1 + adsth; v1 = v1 > 0.f ? v1 : NEG_SLOPE * v1;
        float v2 = av2 + adsth; v2 = v2 > 0.f ? v2 : NEG_SLOPE * v2;
        float v3 = av3 + adsth; v3 = v3 > 0.f ? v3 : NEG_SLOPE * v3;
        float p0 = __expf(v0), p1 = __expf(v1), p2 = __expf(v2), p3 = __expf(v3);
        den += (p0 + p1) + (p2 + p3);
        U += p0 * h0 + p1 * h1 + p2 * h2v + p3 * h3v;
    }
    for (; j < end; j++) {
        int s = src_csr[j];
        float av = asrc[s * HEADS + h];
        float hvv = h_tab[s * OUT_C + c];
        float v = av + adsth; v = v > 0.f ? v : NEG_SLOPE * v;
        float pe = __expf(v);
        den += pe;
        U += pe * hvv;
    }
    U_all[(size_t)n * 64 + lane] = U / (den + 1e-16f);
}

// ---------- K_fuse v3: pipe-split (LDS + TA/L1 in parallel) ----------
// LDS-pipe was saturated in v2 (~850 LDS wave-instrs/wave). v3:
//  - gat_lin read from GLOBAL (L1-resident, 8-way broadcast)  -> -256 ds_read_b64
//  - fc_w split: cols 0..63 via LDS (waves 0,2), 64..127 via global (waves 1,3)
//  - only sA + half-sW staged; LDS 6.9 KB
#define FBM 32
__global__ __launch_bounds__(256) void k_fuse(
    const float* __restrict__ U_all, const float* __restrict__ gat_lin,
    const float* __restrict__ gat_bias, const float* __restrict__ fc_w,
    const float* __restrict__ fc_b, float* __restrict__ y)
{
    __shared__ float sA[16][FBM + 4];     // 2.3 KB, pitch 36
    __shared__ float sW[16][64];          // 4 KB, cols 0..63 of current k-tile
    int tid = threadIdx.x;
    int r0 = blockIdx.x * FBM;

    // G-gen mapping: 32 rows x 8 col-pairs
    int ar  = tid >> 3;          // 0..31  row within tile
    int ak  = (tid & 7) * 2;     // 0,2,..,14 column pair within 16-wide k-tile
    int grow = r0 + ar;

    // mm mapping: wave-specialized column halves (wave-uniform LDS/global path)
    int w    = tid >> 6;                       // wave 0..3
    int lane = tid & 63;
    int trow = (w >> 1) * 16 + (lane >> 4) * 4;   // waves 0,1: rows 0..15; 2,3: 16..31
    int tcol = (w & 1) * 64 + (lane & 15) * 4;    // waves 0,2: cols 0..63 (LDS)
    bool useLds = ((w & 1) == 0);

    // W staging mapping (cols 0..63 of tile): 16 rows x 16 float4s
    int skk = tid >> 4;          // 0..15
    int scc = (tid & 15) * 4;    // 0..60

    float acc[4][4];
#pragma unroll
    for (int r = 0; r < 4; r++)
#pragma unroll
        for (int c = 0; c < 4; c++) acc[r][c] = 0.f;

    for (int h = 0; h < HEADS; ++h) {
        // this thread's U row slice for head h, kept in registers
        float4 ua = make_float4(0.f, 0.f, 0.f, 0.f), ub = ua, uc4 = ua, ud = ua;
        if (grow < N_NODES) {
            const float4* up = (const float4*)&U_all[(size_t)grow * 64 + h * 16];
            ua = up[0]; ub = up[1]; uc4 = up[2]; ud = up[3];
        }
        float ureg[16] = {ua.x, ua.y, ua.z, ua.w,  ub.x, ub.y, ub.z, ub.w,
                          uc4.x, uc4.y, uc4.z, uc4.w,  ud.x, ud.y, ud.z, ud.w};

#pragma unroll
        for (int tt = 0; tt < 4; ++tt) {
            int k0 = h * 64 + tt * 16;
            float b0 = gat_bias[k0 + ak];
            float b1 = gat_bias[k0 + ak + 1];
            float g0 = 0.f, g1 = 0.f;
#pragma unroll
            for (int c = 0; c < 16; ++c) {
                // global read: 8 distinct 8B addrs per wave-instr, L1-resident
                const float* lp = &gat_lin[c * GDIM + k0 + ak];
                g0 += ureg[c] * lp[0];
                g1 += ureg[c] * lp[1];
            }
            __syncthreads();   // previous tile's mm reads complete
            sA[ak][ar]     = fmaxf(g0 + b0, 0.f);
            sA[ak + 1][ar] = fmaxf(g1 + b1, 0.f);
            *(float4*)&sW[skk][scc] =
                *(const float4*)&fc_w[(size_t)(k0 + skk) * FINAL + scc];
            __syncthreads();   // sA/sW ready

            if (useLds) {
#pragma unroll
                for (int kk = 0; kk < 16; ++kk) {
                    float4 wv = *(const float4*)&sW[kk][tcol];
                    float4 a = *(const float4*)&sA[kk][trow];
                    float av[4] = {a.x, a.y, a.z, a.w};
#pragma unroll
                    for (int r = 0; r < 4; r++) {
                        acc[r][0] += av[r] * wv.x;
                        acc[r][1] += av[r] * wv.y;
                        acc[r][2] += av[r] * wv.z;
                        acc[r][3] += av[r] * wv.w;
                    }
                }
            } else {
#pragma unroll
                for (int kk = 0; kk < 16; ++kk) {
                    float4 wv = *(const float4*)&fc_w[(size_t)(k0 + kk) * FINAL + tcol];
                    float4 a = *(const float4*)&sA[kk][trow];
                    float av[4] = {a.x, a.y, a.z, a.w};
#pragma unroll
                    for (int r = 0; r < 4; r++) {
                        acc[r][0] += av[r] * wv.x;
                        acc[r][1] += av[r] * wv.y;
                        acc[r][2] += av[r] * wv.z;
                        acc[r][3] += av[r] * wv.w;
                    }
                }
            }
        }
    }

    float4 fb = *(const float4*)&fc_b[tcol];
#pragma unroll
    for (int r = 0; r < 4; r++) {
        int row = r0 + trow + r;
        if (row < N_NODES) {
            *(float4*)&y[(size_t)row * FINAL + tcol] =
                make_float4(acc[r][0] + fb.x, acc[r][1] + fb.y,
                            acc[r][2] + fb.z, acc[r][3] + fb.w);
        }
    }
}

extern "C" void kernel_launch(void* const* d_in, const int* in_sizes, int n_in,
                              void* d_out, int out_size, void* d_ws, size_t ws_size,
                              hipStream_t stream)
{
    const float* x        = (const float*)d_in[0];
    const int*   ei       = (const int*)d_in[1];
    const float* ea       = (const float*)d_in[2];
    const float* ecc_root = (const float*)d_in[3];
    const float* ecc_bias = (const float*)d_in[4];
    const float* mlp_w    = (const float*)d_in[5];
    const float* mlp_b    = (const float*)d_in[6];
    const float* gat_lin  = (const float*)d_in[7];
    const float* att_src  = (const float*)d_in[8];
    const float* att_dst  = (const float*)d_in[9];
    const float* gat_bias = (const float*)d_in[10];
    const float* fc_w     = (const float*)d_in[11];
    const float* fc_b     = (const float*)d_in[12];
    float* y = (float*)d_out;

    const int* src = ei;
    const int* dst = ei + N_EDGES;

    // workspace layout (~50.0 MB total)
    float* h_tab = (float*)d_ws;                                  // N*16  (3.2 MB)
    float* U_all = h_tab + (size_t)N_NODES * OUT_C;               // N*64  (12.8 MB)
    float* asrc  = U_all + (size_t)N_NODES * 64;                  // N*4
    float* adst  = asrc + (size_t)N_NODES * HEADS;                // N*4
    float* wsrc  = adst + (size_t)N_NODES * HEADS;                // 64
    float* wdst  = wsrc + 64;                                     // 64
    int*   cnt      = (int*)(wdst + 64);                          // N
    int*   offs     = cnt + N_NODES;                              // N+4 (padded for 16B alignment downstream)
    int*   part     = offs + N_NODES + 4;                         // 256
    int*   partscan = part + 256;                                 // 256
    int*   rnk      = partscan + 256;                             // E
    int*   src_csr  = rnk + N_EDGES;                              // E
    float* ea_csr   = (float*)(src_csr + N_EDGES);                // E*8 (25.6 MB, 16B-aligned)

    hipMemsetAsync(cnt, 0, sizeof(int) * N_NODES, stream);

    k_histfold<<<EB + 1, 256, 0, stream>>>(dst, cnt, rnk, gat_lin, att_src, att_dst,
                                           wsrc, wdst);
    k_part    <<<NBLK, 256, 0, stream>>>(cnt, part);
    k_scan1   <<<1, 256, 0, stream>>>(part, partscan);
    k_add     <<<NBLK, 256, 0, stream>>>(cnt, partscan, offs);
    k_scatter <<<EB, 256, 0, stream>>>(src, dst, rnk, offs, ea, src_csr, ea_csr);

    k2T_wave  <<<N_NODES / 4, 256, 0, stream>>>(x, src_csr, offs, ea_csr, mlp_w, mlp_b,
                                                ecc_root, ecc_bias, wsrc, wdst,
                                                h_tab, asrc, adst);
    k_gatE    <<<N_NODES / 4, 256, 0, stream>>>(offs, src_csr, asrc, adst, h_tab, U_all);
    k_fuse    <<<(N_NODES + FBM - 1) / FBM, 256, 0, stream>>>(U_all, gat_lin, gat_bias,
                                                              fc_w, fc_b, y);
}

// Round 4
// 351.813 us; speedup vs baseline: 1.0917x; 1.0917x over previous
//
#include <hip/hip_runtime.h>

#define N_NODES 50000
#define N_EDGES 800000
#define IN_C 8
#define OUT_C 16
#define EDGE_F 8
#define HEADS 4
#define HID 64
#define GDIM (HEADS*HID)   // 256
#define FINAL 128
#define NEG_SLOPE 0.2f
#define EB ((N_EDGES+255)/256)      // 3125
#define NBLK 196                    // ceil(N_NODES/256)

__device__ __forceinline__ int clampn(int v) {
    return v < 0 ? 0 : (v >= N_NODES ? N_NODES - 1 : v);
}

// ---------- K_histfold: dst histogram + rank, plus folded attention weights ----------
__global__ __launch_bounds__(256) void k_histfold(
    const int* __restrict__ dst, int* __restrict__ cnt, int* __restrict__ rnk,
    const float* __restrict__ gat_lin,
    const float* __restrict__ att_src_w, const float* __restrict__ att_dst_w,
    float* __restrict__ wsrc, float* __restrict__ wdst)
{
    if (blockIdx.x < EB) {
        int e = blockIdx.x * 256 + threadIdx.x;
        if (e >= N_EDGES) return;
        rnk[e] = atomicAdd(&cnt[clampn(dst[e])], 1);
    } else {
        int t = threadIdx.x;           // t = c*4 + h
        if (t >= 64) return;
        int c = t >> 2, h = t & 3;
        float ws = 0.f, wd = 0.f;
        for (int k = 0; k < HID; k++) {
            float l = gat_lin[c * GDIM + h * HID + k];
            ws += l * att_src_w[h * HID + k];
            wd += l * att_dst_w[h * HID + k];
        }
        wsrc[t] = ws;
        wdst[t] = wd;
    }
}

// ---------- scan pipeline ----------
__global__ __launch_bounds__(256) void k_part(const int* __restrict__ cnt,
                                              int* __restrict__ part)
{
    int i = blockIdx.x * 256 + threadIdx.x;
    int v = (i < N_NODES) ? cnt[i] : 0;
#pragma unroll
    for (int off = 32; off; off >>= 1) v += __shfl_down(v, off);
    __shared__ int ws[4];
    if ((threadIdx.x & 63) == 0) ws[threadIdx.x >> 6] = v;
    __syncthreads();
    if (threadIdx.x == 0) part[blockIdx.x] = ws[0] + ws[1] + ws[2] + ws[3];
}

__global__ __launch_bounds__(256) void k_scan1(const int* __restrict__ part,
                                               int* __restrict__ partscan)
{
    int t = threadIdx.x;
    int v = (t < NBLK) ? part[t] : 0;
    int lane = t & 63, wid = t >> 6;
    int incl = v;
#pragma unroll
    for (int off = 1; off < 64; off <<= 1) {
        int u = __shfl_up(incl, off);
        if (lane >= off) incl += u;
    }
    __shared__ int wsum[4];
    if (lane == 63) wsum[wid] = incl;
    __syncthreads();
    int add = 0;
    for (int w = 0; w < wid; w++) add += wsum[w];
    partscan[t] = incl - v + add;   // exclusive
}

__global__ __launch_bounds__(256) void k_add(const int* __restrict__ cnt,
                                             const int* __restrict__ partscan,
                                             int* __restrict__ offs)
{
    int i = blockIdx.x * 256 + threadIdx.x;
    int v = (i < N_NODES) ? cnt[i] : 0;
    int lane = threadIdx.x & 63, wid = threadIdx.x >> 6;
    int incl = v;
#pragma unroll
    for (int off = 1; off < 64; off <<= 1) {
        int u = __shfl_up(incl, off);
        if (lane >= off) incl += u;
    }
    __shared__ int wsum[4];
    if (lane == 63) wsum[wid] = incl;
    __syncthreads();
    int add = partscan[blockIdx.x];
    for (int w = 0; w < wid; w++) add += wsum[w];
    if (i < N_NODES) offs[i] = incl - v + add;
    if (i == 0) offs[N_NODES] = N_EDGES;
}

// ---------- K_scatter: build CSR src list AND CSR-ordered edge-attr copy ----------
__global__ __launch_bounds__(256) void k_scatter(
    const int* __restrict__ src, const int* __restrict__ dst,
    const int* __restrict__ rnk, const int* __restrict__ offs,
    const float* __restrict__ ea,
    int* __restrict__ src_csr, float* __restrict__ ea_csr)
{
    int e = blockIdx.x * 256 + threadIdx.x;
    if (e >= N_EDGES) return;
    int p = offs[clampn(dst[e])] + rnk[e];
    src_csr[p] = clampn(src[e]);
    const float4* s4 = (const float4*)&ea[(size_t)e * EDGE_F];
    float4* d4 = (float4*)&ea_csr[(size_t)p * EDGE_F];
    d4[0] = s4[0];
    d4[1] = s4[1];
}

// ---------- K2T: wave-per-node T-factorized NNConv, p-parallel epilogue ----------
// ea CSR-ordered -> sequential streaming reads instead of random 32B gathers.
__global__ __launch_bounds__(256) void k2T_wave(
    const float* __restrict__ x,
    const int* __restrict__ src_csr, const int* __restrict__ offs,
    const float* __restrict__ ea_csr,
    const float* __restrict__ mlp_w, const float* __restrict__ mlp_b,
    const float* __restrict__ ecc_root, const float* __restrict__ ecc_bias,
    const float* __restrict__ wsrc, const float* __restrict__ wdst,
    float* __restrict__ h_tab, float* __restrict__ asrc, float* __restrict__ adst)
{
    __shared__ float smW[64 * 17];   // [jj][o] pitch-17 (bank-friendly)
    __shared__ float smb[128];
    __shared__ float sroot[128];
    __shared__ float sbias[16];
    __shared__ float sws[64], swd[64];
    __shared__ float sT[4][64];
    __shared__ float sxs[4][8];

    int t = threadIdx.x;
    for (int idx = t; idx < 1024; idx += 256)
        smW[(idx >> 4) * 17 + (idx & 15)] = mlp_w[idx];
    if (t < 128) smb[t] = mlp_b[t];
    if (t >= 128 && t < 256) sroot[t - 128] = ecc_root[t - 128];
    if (t < 16) sbias[t] = ecc_bias[t];
    if (t >= 32 && t < 96) sws[t - 32] = wsrc[t - 32];
    if (t >= 96 && t < 160) swd[t - 96] = wdst[t - 96];

    int wid = t >> 6, lane = t & 63;
    int n = blockIdx.x * 4 + wid;   // grid = 12500 exactly
    int f = lane >> 3, i = lane & 7;
    int beg = offs[n], end = offs[n + 1];

    float t0 = 0.f, t1 = 0.f, t2 = 0.f, t3 = 0.f, xs = 0.f;
    int j = beg;
    for (; j + 3 < end; j += 4) {
        int s0 = src_csr[j],     s1 = src_csr[j + 1];
        int s2 = src_csr[j + 2], s3 = src_csr[j + 3];
        float a0 = ea_csr[(size_t)j * EDGE_F + f];
        float a1 = ea_csr[(size_t)(j + 1) * EDGE_F + f];
        float a2 = ea_csr[(size_t)(j + 2) * EDGE_F + f];
        float a3 = ea_csr[(size_t)(j + 3) * EDGE_F + f];
        float x0 = x[s0 * IN_C + i];
        float x1 = x[s1 * IN_C + i];
        float x2 = x[s2 * IN_C + i];
        float x3 = x[s3 * IN_C + i];
        t0 += a0 * x0; t1 += a1 * x1; t2 += a2 * x2; t3 += a3 * x3;
        xs += (x0 + x1) + (x2 + x3);
    }
    for (; j < end; j++) {
        int s = src_csr[j];
        float a = ea_csr[(size_t)j * EDGE_F + f];
        float xv = x[s * IN_C + i];
        t0 += a * xv;
        xs += xv;
    }
    sT[wid][lane] = (t0 + t1) + (t2 + t3);
    if (f == 0) sxs[wid][i] = xs;
    __syncthreads();     // covers LDS preloads + sT/sxs

    // p-parallel 64x16 contraction: lane = p*16 + o, partial over jj=p*16..+15
    int o = lane & 15, p = lane >> 4;
    float v = 0.f;
#pragma unroll
    for (int q2 = 0; q2 < 16; q2++) {
        int jj = p * 16 + q2;
        v += smW[jj * 17 + o] * sT[wid][jj];
    }
    v += __shfl_down(v, 32);
    v += __shfl_down(v, 16);    // lanes<16 hold full sums

    float hv = 0.f;
    if (lane < 16) {
        float vv = v + sbias[o];
#pragma unroll
        for (int ii = 0; ii < IN_C; ii++) {
            vv += smb[ii * 16 + o] * sxs[wid][ii];
            vv += x[n * IN_C + ii] * sroot[ii * 16 + o];
        }
        hv = fmaxf(vv, 0.f);
        h_tab[n * OUT_C + o] = hv;
    }
    // folded attention logits
    float as = 0.f, ad = 0.f;
    int h2 = lane & 3;
#pragma unroll
    for (int c = 0; c < 16; c++) {
        float hc = __shfl(hv, c);
        as += hc * sws[c * 4 + h2];
        ad += hc * swd[c * 4 + h2];
    }
    if (lane < 4) {
        asrc[n * HEADS + lane] = as;
        adst[n * HEADS + lane] = ad;
    }
}

// ---------- K_gatE: wave-per-node U accumulation, normalized in-register ----------
// lane = h*16+c; den is identical across the 16 lanes of a head -> no reduce.
__global__ __launch_bounds__(256) void k_gatE(
    const int* __restrict__ offs, const int* __restrict__ src_csr,
    const float* __restrict__ asrc, const float* __restrict__ adst,
    const float* __restrict__ h_tab, float* __restrict__ U_all)
{
    int t = threadIdx.x;
    int wid = t >> 6, lane = t & 63;
    int n = blockIdx.x * 4 + wid;   // grid = 12500 exactly
    int h = lane >> 4, c = lane & 15;
    float adsth = adst[n * HEADS + h];
    int beg = offs[n], end = offs[n + 1];

    float U = 0.f, den = 0.f;
    int j = beg;
    for (; j + 3 < end; j += 4) {
        int s0 = src_csr[j],     s1 = src_csr[j + 1];
        int s2 = src_csr[j + 2], s3 = src_csr[j + 3];
        float av0 = asrc[s0 * HEADS + h], av1 = asrc[s1 * HEADS + h];
        float av2 = asrc[s2 * HEADS + h], av3 = asrc[s3 * HEADS + h];
        float h0 = h_tab[s0 * OUT_C + c], h1 = h_tab[s1 * OUT_C + c];
        float h2v = h_tab[s2 * OUT_C + c], h3v = h_tab[s3 * OUT_C + c];
        float v0 = av0 + adsth; v0 = v0 > 0.f ? v0 : NEG_SLOPE * v0;
        float v1 = av1 + adsth; v1 = v1 > 0.f ? v1 : NEG_SLOPE * v1;
        float v2 = av2 + adsth; v2 = v2 > 0.f ? v2 : NEG_SLOPE * v2;
        float v3 = av3 + adsth; v3 = v3 > 0.f ? v3 : NEG_SLOPE * v3;
        float p0 = __expf(v0), p1 = __expf(v1), p2 = __expf(v2), p3 = __expf(v3);
        den += (p0 + p1) + (p2 + p3);
        U += p0 * h0 + p1 * h1 + p2 * h2v + p3 * h3v;
    }
    for (; j < end; j++) {
        int s = src_csr[j];
        float av = asrc[s * HEADS + h];
        float hvv = h_tab[s * OUT_C + c];
        float v = av + adsth; v = v > 0.f ? v : NEG_SLOPE * v;
        float pe = __expf(v);
        den += pe;
        U += pe * hvv;
    }
    U_all[(size_t)n * 64 + lane] = U / (den + 1e-16f);
}

// ---------- K_fuse v4: all-LDS, 4x8 thread tile (32 FMA per 3 ds_read_b128) ----------
// y = relu( (Unorm @ blockdiag(gat_lin)) + gat_bias ) @ fc_w + fc_b
// 128 threads (2 waves), FBM=32 rows x 128 cols; LDS 26.3 KB -> 6 blocks/CU.
// A-reads: 4 distinct addrs/wave (broadcast); W-reads: 16 distinct (quad-aliased);
// G-gen slin reads: 4 distinct addrs/wave (broadcast).
#define FBM 32
__global__ __launch_bounds__(128) void k_fuse(
    const float* __restrict__ U_all, const float* __restrict__ gat_lin,
    const float* __restrict__ gat_bias, const float* __restrict__ fc_w,
    const float* __restrict__ fc_b, float* __restrict__ y)
{
    __shared__ float slin[16 * GDIM];     // 16 KB (whole gat_lin [16][256])
    __shared__ float sA[16][FBM + 4];     // 2.3 KB, pitch 36 (144B = 9x16B aligned)
    __shared__ float sW[16][FINAL];       // 8 KB
    int tid = threadIdx.x;
    int r0 = blockIdx.x * FBM;

    for (int idx = tid; idx < (16 * GDIM) / 4; idx += 128)
        ((float4*)slin)[idx] = ((const float4*)gat_lin)[idx];
    __syncthreads();    // slin visible before first G-gen

    // G-gen mapping: 32 rows x 4 col-quads
    int ar  = tid >> 2;          // 0..31  row within tile
    int akq = (tid & 3) * 4;     // 0,4,8,12: col quad within 16-wide k-tile
    int grow = r0 + ar;

    // mm mapping: 4 rows x 8 cols per thread
    int rg = tid >> 4;           // 0..7  -> rows rg*4..+3
    int cg = tid & 15;           // 0..15 -> cols cg*8..+7

    // sW staging mapping: 16 rows x 8 col-octs (4 float4 each)
    int skk = tid >> 3;          // 0..15
    int scc = (tid & 7) * 16;    // 0,16,..,112

    float acc[4][8];
#pragma unroll
    for (int r = 0; r < 4; r++)
#pragma unroll
        for (int c = 0; c < 8; c++) acc[r][c] = 0.f;

    for (int h = 0; h < HEADS; ++h) {
        // this thread's U row slice for head h, kept in registers
        float4 ua = make_float4(0.f, 0.f, 0.f, 0.f), ub = ua, uc4 = ua, ud = ua;
        if (grow < N_NODES) {
            const float4* up = (const float4*)&U_all[(size_t)grow * 64 + h * 16];
            ua = up[0]; ub = up[1]; uc4 = up[2]; ud = up[3];
        }
        float ureg[16] = {ua.x, ua.y, ua.z, ua.w,  ub.x, ub.y, ub.z, ub.w,
                          uc4.x, uc4.y, uc4.z, uc4.w,  ud.x, ud.y, ud.z, ud.w};

#pragma unroll
        for (int tt = 0; tt < 4; ++tt) {
            int k0 = h * 64 + tt * 16;
            float4 bv = *(const float4*)&gat_bias[k0 + akq];
            float g0 = 0.f, g1 = 0.f, g2 = 0.f, g3 = 0.f;
#pragma unroll
            for (int c = 0; c < 16; ++c) {
                float4 lv = *(const float4*)&slin[c * GDIM + k0 + akq];
                g0 += ureg[c] * lv.x;
                g1 += ureg[c] * lv.y;
                g2 += ureg[c] * lv.z;
                g3 += ureg[c] * lv.w;
            }
            __syncthreads();   // previous tile's mm reads complete
            sA[akq + 0][ar] = fmaxf(g0 + bv.x, 0.f);
            sA[akq + 1][ar] = fmaxf(g1 + bv.y, 0.f);
            sA[akq + 2][ar] = fmaxf(g2 + bv.z, 0.f);
            sA[akq + 3][ar] = fmaxf(g3 + bv.w, 0.f);
            {
                const float4* wsrc4 =
                    (const float4*)&fc_w[(size_t)(k0 + skk) * FINAL + scc];
                float4* wdst4 = (float4*)&sW[skk][scc];
                wdst4[0] = wsrc4[0];
                wdst4[1] = wsrc4[1];
                wdst4[2] = wsrc4[2];
                wdst4[3] = wsrc4[3];
            }
            __syncthreads();   // sA/sW ready
#pragma unroll
            for (int kk = 0; kk < 16; ++kk) {
                float4 a  = *(const float4*)&sA[kk][rg * 4];
                float4 w0 = *(const float4*)&sW[kk][cg * 8];
                float4 w1 = *(const float4*)&sW[kk][cg * 8 + 4];
                float av[4] = {a.x, a.y, a.z, a.w};
#pragma unroll
                for (int r = 0; r < 4; r++) {
                    acc[r][0] += av[r] * w0.x;
                    acc[r][1] += av[r] * w0.y;
                    acc[r][2] += av[r] * w0.z;
                    acc[r][3] += av[r] * w0.w;
                    acc[r][4] += av[r] * w1.x;
                    acc[r][5] += av[r] * w1.y;
                    acc[r][6] += av[r] * w1.z;
                    acc[r][7] += av[r] * w1.w;
                }
            }
        }
    }

    float4 fb0 = *(const float4*)&fc_b[cg * 8];
    float4 fb1 = *(const float4*)&fc_b[cg * 8 + 4];
#pragma unroll
    for (int r = 0; r < 4; r++) {
        int row = r0 + rg * 4 + r;
        if (row < N_NODES) {
            float* yp = &y[(size_t)row * FINAL + cg * 8];
            *(float4*)&yp[0] = make_float4(acc[r][0] + fb0.x, acc[r][1] + fb0.y,
                                           acc[r][2] + fb0.z, acc[r][3] + fb0.w);
            *(float4*)&yp[4] = make_float4(acc[r][4] + fb1.x, acc[r][5] + fb1.y,
                                           acc[r][6] + fb1.z, acc[r][7] + fb1.w);
        }
    }
}

extern "C" void kernel_launch(void* const* d_in, const int* in_sizes, int n_in,
                              void* d_out, int out_size, void* d_ws, size_t ws_size,
                              hipStream_t stream)
{
    const float* x        = (const float*)d_in[0];
    const int*   ei       = (const int*)d_in[1];
    const float* ea       = (const float*)d_in[2];
    const float* ecc_root = (const float*)d_in[3];
    const float* ecc_bias = (const float*)d_in[4];
    const float* mlp_w    = (const float*)d_in[5];
    const float* mlp_b    = (const float*)d_in[6];
    const float* gat_lin  = (const float*)d_in[7];
    const float* att_src  = (const float*)d_in[8];
    const float* att_dst  = (const float*)d_in[9];
    const float* gat_bias = (const float*)d_in[10];
    const float* fc_w     = (const float*)d_in[11];
    const float* fc_b     = (const float*)d_in[12];
    float* y = (float*)d_out;

    const int* src = ei;
    const int* dst = ei + N_EDGES;

    // workspace layout (~50.0 MB total)
    float* h_tab = (float*)d_ws;                                  // N*16  (3.2 MB)
    float* U_all = h_tab + (size_t)N_NODES * OUT_C;               // N*64  (12.8 MB)
    float* asrc  = U_all + (size_t)N_NODES * 64;                  // N*4
    float* adst  = asrc + (size_t)N_NODES * HEADS;                // N*4
    float* wsrc  = adst + (size_t)N_NODES * HEADS;                // 64
    float* wdst  = wsrc + 64;                                     // 64
    int*   cnt      = (int*)(wdst + 64);                          // N
    int*   offs     = cnt + N_NODES;                              // N+4 (padded for 16B alignment downstream)
    int*   part     = offs + N_NODES + 4;                         // 256
    int*   partscan = part + 256;                                 // 256
    int*   rnk      = partscan + 256;                             // E
    int*   src_csr  = rnk + N_EDGES;                              // E
    float* ea_csr   = (float*)(src_csr + N_EDGES);                // E*8 (25.6 MB, 16B-aligned)

    hipMemsetAsync(cnt, 0, sizeof(int) * N_NODES, stream);

    k_histfold<<<EB + 1, 256, 0, stream>>>(dst, cnt, rnk, gat_lin, att_src, att_dst,
                                           wsrc, wdst);
    k_part    <<<NBLK, 256, 0, stream>>>(cnt, part);
    k_scan1   <<<1, 256, 0, stream>>>(part, partscan);
    k_add     <<<NBLK, 256, 0, stream>>>(cnt, partscan, offs);
    k_scatter <<<EB, 256, 0, stream>>>(src, dst, rnk, offs, ea, src_csr, ea_csr);

    k2T_wave  <<<N_NODES / 4, 256, 0, stream>>>(x, src_csr, offs, ea_csr, mlp_w, mlp_b,
                                                ecc_root, ecc_bias, wsrc, wdst,
                                                h_tab, asrc, adst);
    k_gatE    <<<N_NODES / 4, 256, 0, stream>>>(offs, src_csr, asrc, adst, h_tab, U_all);
    k_fuse    <<<(N_NODES + FBM - 1) / FBM, 128, 0, stream>>>(U_all, gat_lin, gat_bias,
                                                              fc_w, fc_b, y);
}

// Round 5
// 313.141 us; speedup vs baseline: 1.2265x; 1.1235x over previous
//
#include <hip/hip_runtime.h>

#define N_NODES 50000
#define N_EDGES 800000
#define IN_C 8
#define OUT_C 16
#define EDGE_F 8
#define HEADS 4
#define HID 64
#define GDIM (HEADS*HID)   // 256
#define FINAL 128
#define NEG_SLOPE 0.2f
#define EB ((N_EDGES+255)/256)      // 3125
#define NBLK 196                    // ceil(N_NODES/256)

__device__ __forceinline__ int clampn(int v) {
    return v < 0 ? 0 : (v >= N_NODES ? N_NODES - 1 : v);
}

// ---------- K_histfold: dst histogram + rank, plus folded attention weights ----------
__global__ __launch_bounds__(256) void k_histfold(
    const int* __restrict__ dst, int* __restrict__ cnt, int* __restrict__ rnk,
    const float* __restrict__ gat_lin,
    const float* __restrict__ att_src_w, const float* __restrict__ att_dst_w,
    float* __restrict__ wsrc, float* __restrict__ wdst)
{
    if (blockIdx.x < EB) {
        int e = blockIdx.x * 256 + threadIdx.x;
        if (e >= N_EDGES) return;
        rnk[e] = atomicAdd(&cnt[clampn(dst[e])], 1);
    } else {
        int t = threadIdx.x;           // t = c*4 + h
        if (t >= 64) return;
        int c = t >> 2, h = t & 3;
        float ws = 0.f, wd = 0.f;
        for (int k = 0; k < HID; k++) {
            float l = gat_lin[c * GDIM + h * HID + k];
            ws += l * att_src_w[h * HID + k];
            wd += l * att_dst_w[h * HID + k];
        }
        wsrc[t] = ws;
        wdst[t] = wd;
    }
}

// ---------- scan pipeline ----------
__global__ __launch_bounds__(256) void k_part(const int* __restrict__ cnt,
                                              int* __restrict__ part)
{
    int i = blockIdx.x * 256 + threadIdx.x;
    int v = (i < N_NODES) ? cnt[i] : 0;
#pragma unroll
    for (int off = 32; off; off >>= 1) v += __shfl_down(v, off);
    __shared__ int ws[4];
    if ((threadIdx.x & 63) == 0) ws[threadIdx.x >> 6] = v;
    __syncthreads();
    if (threadIdx.x == 0) part[blockIdx.x] = ws[0] + ws[1] + ws[2] + ws[3];
}

__global__ __launch_bounds__(256) void k_scan1(const int* __restrict__ part,
                                               int* __restrict__ partscan)
{
    int t = threadIdx.x;
    int v = (t < NBLK) ? part[t] : 0;
    int lane = t & 63, wid = t >> 6;
    int incl = v;
#pragma unroll
    for (int off = 1; off < 64; off <<= 1) {
        int u = __shfl_up(incl, off);
        if (lane >= off) incl += u;
    }
    __shared__ int wsum[4];
    if (lane == 63) wsum[wid] = incl;
    __syncthreads();
    int add = 0;
    for (int w = 0; w < wid; w++) add += wsum[w];
    partscan[t] = incl - v + add;   // exclusive
}

__global__ __launch_bounds__(256) void k_add(const int* __restrict__ cnt,
                                             const int* __restrict__ partscan,
                                             int* __restrict__ offs)
{
    int i = blockIdx.x * 256 + threadIdx.x;
    int v = (i < N_NODES) ? cnt[i] : 0;
    int lane = threadIdx.x & 63, wid = threadIdx.x >> 6;
    int incl = v;
#pragma unroll
    for (int off = 1; off < 64; off <<= 1) {
        int u = __shfl_up(incl, off);
        if (lane >= off) incl += u;
    }
    __shared__ int wsum[4];
    if (lane == 63) wsum[wid] = incl;
    __syncthreads();
    int add = partscan[blockIdx.x];
    for (int w = 0; w < wid; w++) add += wsum[w];
    if (i < N_NODES) offs[i] = incl - v + add;
    if (i == 0) offs[N_NODES] = N_EDGES;
}

__global__ __launch_bounds__(256) void k_scatter(
    const int* __restrict__ src, const int* __restrict__ dst,
    const int* __restrict__ rnk, const int* __restrict__ offs,
    int2* __restrict__ se_csr)
{
    int e = blockIdx.x * 256 + threadIdx.x;
    if (e >= N_EDGES) return;
    int p = offs[clampn(dst[e])] + rnk[e];
    se_csr[p] = make_int2(clampn(src[e]), e);
}

// ---------- K2T: wave-per-node T-factorized NNConv, p-parallel epilogue ----------
// T[d,f,i] = sum_{e->d} ea[e,f]*x[s_e,i]; h = relu(W.T + b.xs + x@root + bias)
__global__ __launch_bounds__(256) void k2T_wave(
    const float* __restrict__ x,
    const int2* __restrict__ se_csr, const int* __restrict__ offs,
    const float* __restrict__ ea,
    const float* __restrict__ mlp_w, const float* __restrict__ mlp_b,
    const float* __restrict__ ecc_root, const float* __restrict__ ecc_bias,
    const float* __restrict__ wsrc, const float* __restrict__ wdst,
    float* __restrict__ h_tab, float* __restrict__ asrc, float* __restrict__ adst)
{
    __shared__ float smW[64 * 17];   // [jj][o] pitch-17 (bank-friendly)
    __shared__ float smb[128];
    __shared__ float sroot[128];
    __shared__ float sbias[16];
    __shared__ float sws[64], swd[64];
    __shared__ float sT[4][64];
    __shared__ float sxs[4][8];

    int t = threadIdx.x;
    for (int idx = t; idx < 1024; idx += 256)
        smW[(idx >> 4) * 17 + (idx & 15)] = mlp_w[idx];
    if (t < 128) smb[t] = mlp_b[t];
    if (t >= 128 && t < 256) sroot[t - 128] = ecc_root[t - 128];
    if (t < 16) sbias[t] = ecc_bias[t];
    if (t >= 32 && t < 96) sws[t - 32] = wsrc[t - 32];
    if (t >= 96 && t < 160) swd[t - 96] = wdst[t - 96];

    int wid = t >> 6, lane = t & 63;
    int n = blockIdx.x * 4 + wid;   // grid = 12500 exactly
    int f = lane >> 3, i = lane & 7;
    int beg = offs[n], end = offs[n + 1];

    float t0 = 0.f, t1 = 0.f, t2 = 0.f, t3 = 0.f, xs = 0.f;
    int j = beg;
    for (; j + 3 < end; j += 4) {
        int2 se0 = se_csr[j],     se1 = se_csr[j + 1];
        int2 se2 = se_csr[j + 2], se3 = se_csr[j + 3];
        float a0 = ea[(size_t)se0.y * EDGE_F + f];
        float a1 = ea[(size_t)se1.y * EDGE_F + f];
        float a2 = ea[(size_t)se2.y * EDGE_F + f];
        float a3 = ea[(size_t)se3.y * EDGE_F + f];
        float x0 = x[se0.x * IN_C + i];
        float x1 = x[se1.x * IN_C + i];
        float x2 = x[se2.x * IN_C + i];
        float x3 = x[se3.x * IN_C + i];
        t0 += a0 * x0; t1 += a1 * x1; t2 += a2 * x2; t3 += a3 * x3;
        xs += (x0 + x1) + (x2 + x3);
    }
    for (; j < end; j++) {
        int2 se = se_csr[j];
        float a = ea[(size_t)se.y * EDGE_F + f];
        float xv = x[se.x * IN_C + i];
        t0 += a * xv;
        xs += xv;
    }
    sT[wid][lane] = (t0 + t1) + (t2 + t3);
    if (f == 0) sxs[wid][i] = xs;
    __syncthreads();     // covers LDS preloads + sT/sxs

    // p-parallel 64x16 contraction: lane = p*16 + o, partial over jj=p*16..+15
    int o = lane & 15, p = lane >> 4;
    float v = 0.f;
#pragma unroll
    for (int q2 = 0; q2 < 16; q2++) {
        int jj = p * 16 + q2;
        v += smW[jj * 17 + o] * sT[wid][jj];
    }
    v += __shfl_down(v, 32);
    v += __shfl_down(v, 16);    // lanes<16 hold full sums

    float hv = 0.f;
    if (lane < 16) {
        float vv = v + sbias[o];
#pragma unroll
        for (int ii = 0; ii < IN_C; ii++) {
            vv += smb[ii * 16 + o] * sxs[wid][ii];
            vv += x[n * IN_C + ii] * sroot[ii * 16 + o];
        }
        hv = fmaxf(vv, 0.f);
        h_tab[n * OUT_C + o] = hv;
    }
    // folded attention logits
    float as = 0.f, ad = 0.f;
    int h2 = lane & 3;
#pragma unroll
    for (int c = 0; c < 16; c++) {
        float hc = __shfl(hv, c);
        as += hc * sws[c * 4 + h2];
        ad += hc * swd[c * 4 + h2];
    }
    if (lane < 4) {
        asrc[n * HEADS + lane] = as;
        adst[n * HEADS + lane] = ad;
    }
}

// ---------- K_gatE: wave-per-node U accumulation, normalized in-register ----------
// lane = h*16+c; den is identical across the 16 lanes of a head -> no reduce.
__global__ __launch_bounds__(256) void k_gatE(
    const int* __restrict__ offs, const int2* __restrict__ se_csr,
    const float* __restrict__ asrc, const float* __restrict__ adst,
    const float* __restrict__ h_tab, float* __restrict__ U_all)
{
    int t = threadIdx.x;
    int wid = t >> 6, lane = t & 63;
    int n = blockIdx.x * 4 + wid;   // grid = 12500 exactly
    int h = lane >> 4, c = lane & 15;
    float adsth = adst[n * HEADS + h];
    int beg = offs[n], end = offs[n + 1];

    float U = 0.f, den = 0.f;
    int j = beg;
    for (; j + 3 < end; j += 4) {
        int s0 = se_csr[j].x,     s1 = se_csr[j + 1].x;
        int s2 = se_csr[j + 2].x, s3 = se_csr[j + 3].x;
        float av0 = asrc[s0 * HEADS + h], av1 = asrc[s1 * HEADS + h];
        float av2 = asrc[s2 * HEADS + h], av3 = asrc[s3 * HEADS + h];
        float h0 = h_tab[s0 * OUT_C + c], h1 = h_tab[s1 * OUT_C + c];
        float h2v = h_tab[s2 * OUT_C + c], h3v = h_tab[s3 * OUT_C + c];
        float v0 = av0 + adsth; v0 = v0 > 0.f ? v0 : NEG_SLOPE * v0;
        float v1 = av1 + adsth; v1 = v1 > 0.f ? v1 : NEG_SLOPE * v1;
        float v2 = av2 + adsth; v2 = v2 > 0.f ? v2 : NEG_SLOPE * v2;
        float v3 = av3 + adsth; v3 = v3 > 0.f ? v3 : NEG_SLOPE * v3;
        float p0 = __expf(v0), p1 = __expf(v1), p2 = __expf(v2), p3 = __expf(v3);
        den += (p0 + p1) + (p2 + p3);
        U += p0 * h0 + p1 * h1 + p2 * h2v + p3 * h3v;
    }
    for (; j < end; j++) {
        int s = se_csr[j].x;
        float av = asrc[s * HEADS + h];
        float hvv = h_tab[s * OUT_C + c];
        float v = av + adsth; v = v > 0.f ? v : NEG_SLOPE * v;
        float pe = __expf(v);
        den += pe;
        U += pe * hvv;
    }
    U_all[(size_t)n * 64 + lane] = U / (den + 1e-16f);
}

// ---------- K_fuse v5: 256 thr, FBM=64, 4x8 thread tile, split columns ----------
// y = relu( (Unorm @ blockdiag(gat_lin)) + gat_bias ) @ fc_w + fc_b
// Per kk: 3 ds_read_b128 per 32 FMA. Column split {cg*4, cg*4+64} keeps every
// b128 read/store at 16B stride across the wave -> all 32 banks, 2-way (free).
// LDS 28.4 KB; grid 782.
#define FBM 64
__global__ __launch_bounds__(256) void k_fuse(
    const float* __restrict__ U_all, const float* __restrict__ gat_lin,
    const float* __restrict__ gat_bias, const float* __restrict__ fc_w,
    const float* __restrict__ fc_b, float* __restrict__ y)
{
    __shared__ float slin[16 * GDIM];     // 16 KB (whole gat_lin [16][256])
    __shared__ float sA[16][FBM + 4];     // 4.35 KB, pitch 68
    __shared__ float sW[16][FINAL];       // 8 KB
    int tid = threadIdx.x;
    int r0 = blockIdx.x * FBM;

    for (int idx = tid; idx < (16 * GDIM) / 4; idx += 256)
        ((float4*)slin)[idx] = ((const float4*)gat_lin)[idx];
    __syncthreads();    // slin visible before first G-gen

    // G-gen mapping: 64 rows x 4 col-quads
    int ar  = tid >> 2;          // 0..63  row within tile
    int akq = (tid & 3) * 4;     // 0,4,8,12: col quad within 16-wide k-tile
    int grow = r0 + ar;

    // mm mapping: 4 rows x 8 cols (split halves) per thread
    int rg = tid >> 4;           // 0..15 -> rows rg*4..+3
    int cg = tid & 15;           // cols cg*4..+3 and cg*4+64..+67

    // sW staging: 16 rows x (16 quads x 2 halves)
    int skk = tid >> 4;          // 0..15
    int scc = (tid & 15) * 4;    // 0,4,..,60

    float acc[4][8];
#pragma unroll
    for (int r = 0; r < 4; r++)
#pragma unroll
        for (int c = 0; c < 8; c++) acc[r][c] = 0.f;

    for (int h = 0; h < HEADS; ++h) {
        // this thread's U row slice for head h, kept in registers
        float4 ua = make_float4(0.f, 0.f, 0.f, 0.f), ub = ua, uc4 = ua, ud = ua;
        if (grow < N_NODES) {
            const float4* up = (const float4*)&U_all[(size_t)grow * 64 + h * 16];
            ua = up[0]; ub = up[1]; uc4 = up[2]; ud = up[3];
        }
        float ureg[16] = {ua.x, ua.y, ua.z, ua.w,  ub.x, ub.y, ub.z, ub.w,
                          uc4.x, uc4.y, uc4.z, uc4.w,  ud.x, ud.y, ud.z, ud.w};

#pragma unroll
        for (int tt = 0; tt < 4; ++tt) {
            int k0 = h * 64 + tt * 16;
            float4 bv = *(const float4*)&gat_bias[k0 + akq];
            float g0 = 0.f, g1 = 0.f, g2 = 0.f, g3 = 0.f;
#pragma unroll
            for (int c = 0; c < 16; ++c) {
                float4 lv = *(const float4*)&slin[c * GDIM + k0 + akq];
                g0 += ureg[c] * lv.x;
                g1 += ureg[c] * lv.y;
                g2 += ureg[c] * lv.z;
                g3 += ureg[c] * lv.w;
            }
            __syncthreads();   // previous tile's mm reads complete
            sA[akq + 0][ar] = fmaxf(g0 + bv.x, 0.f);
            sA[akq + 1][ar] = fmaxf(g1 + bv.y, 0.f);
            sA[akq + 2][ar] = fmaxf(g2 + bv.z, 0.f);
            sA[akq + 3][ar] = fmaxf(g3 + bv.w, 0.f);
            {
                const float* wrow = &fc_w[(size_t)(k0 + skk) * FINAL];
                *(float4*)&sW[skk][scc]      = *(const float4*)&wrow[scc];
                *(float4*)&sW[skk][scc + 64] = *(const float4*)&wrow[scc + 64];
            }
            __syncthreads();   // sA/sW ready
#pragma unroll
            for (int kk = 0; kk < 16; ++kk) {
                float4 a  = *(const float4*)&sA[kk][rg * 4];
                float4 w0 = *(const float4*)&sW[kk][cg * 4];
                float4 w1 = *(const float4*)&sW[kk][cg * 4 + 64];
                float av[4] = {a.x, a.y, a.z, a.w};
#pragma unroll
                for (int r = 0; r < 4; r++) {
                    acc[r][0] += av[r] * w0.x;
                    acc[r][1] += av[r] * w0.y;
                    acc[r][2] += av[r] * w0.z;
                    acc[r][3] += av[r] * w0.w;
                    acc[r][4] += av[r] * w1.x;
                    acc[r][5] += av[r] * w1.y;
                    acc[r][6] += av[r] * w1.z;
                    acc[r][7] += av[r] * w1.w;
                }
            }
        }
    }

    float4 fb0 = *(const float4*)&fc_b[cg * 4];
    float4 fb1 = *(const float4*)&fc_b[cg * 4 + 64];
#pragma unroll
    for (int r = 0; r < 4; r++) {
        int row = r0 + rg * 4 + r;
        if (row < N_NODES) {
            float* yp = &y[(size_t)row * FINAL];
            *(float4*)&yp[cg * 4] =
                make_float4(acc[r][0] + fb0.x, acc[r][1] + fb0.y,
                            acc[r][2] + fb0.z, acc[r][3] + fb0.w);
            *(float4*)&yp[cg * 4 + 64] =
                make_float4(acc[r][4] + fb1.x, acc[r][5] + fb1.y,
                            acc[r][6] + fb1.z, acc[r][7] + fb1.w);
        }
    }
}

extern "C" void kernel_launch(void* const* d_in, const int* in_sizes, int n_in,
                              void* d_out, int out_size, void* d_ws, size_t ws_size,
                              hipStream_t stream)
{
    const float* x        = (const float*)d_in[0];
    const int*   ei       = (const int*)d_in[1];
    const float* ea       = (const float*)d_in[2];
    const float* ecc_root = (const float*)d_in[3];
    const float* ecc_bias = (const float*)d_in[4];
    const float* mlp_w    = (const float*)d_in[5];
    const float* mlp_b    = (const float*)d_in[6];
    const float* gat_lin  = (const float*)d_in[7];
    const float* att_src  = (const float*)d_in[8];
    const float* att_dst  = (const float*)d_in[9];
    const float* gat_bias = (const float*)d_in[10];
    const float* fc_w     = (const float*)d_in[11];
    const float* fc_b     = (const float*)d_in[12];
    float* y = (float*)d_out;

    const int* src = ei;
    const int* dst = ei + N_EDGES;

    // workspace layout
    float* h_tab = (float*)d_ws;                                  // N*16  (3.2 MB)
    float* U_all = h_tab + (size_t)N_NODES * OUT_C;               // N*64  (12.8 MB)
    float* asrc  = U_all + (size_t)N_NODES * 64;                  // N*4
    float* adst  = asrc + (size_t)N_NODES * HEADS;                // N*4
    float* wsrc  = adst + (size_t)N_NODES * HEADS;                // 64
    float* wdst  = wsrc + 64;                                     // 64
    int*   cnt      = (int*)(wdst + 64);                          // N
    int*   offs     = cnt + N_NODES;                              // N+1
    int*   part     = offs + N_NODES + 1;                         // 256
    int*   partscan = part + 256;                                 // 256
    int*   rnk      = partscan + 256;                             // E
    int2*  se_csr   = (int2*)(rnk + N_EDGES + 1);                 // E int2 (8B-aligned)

    hipMemsetAsync(cnt, 0, sizeof(int) * N_NODES, stream);

    k_histfold<<<EB + 1, 256, 0, stream>>>(dst, cnt, rnk, gat_lin, att_src, att_dst,
                                           wsrc, wdst);
    k_part    <<<NBLK, 256, 0, stream>>>(cnt, part);
    k_scan1   <<<1, 256, 0, stream>>>(part, partscan);
    k_add     <<<NBLK, 256, 0, stream>>>(cnt, partscan, offs);
    k_scatter <<<EB, 256, 0, stream>>>(src, dst, rnk, offs, se_csr);

    k2T_wave  <<<N_NODES / 4, 256, 0, stream>>>(x, se_csr, offs, ea, mlp_w, mlp_b,
                                                ecc_root, ecc_bias, wsrc, wdst,
                                                h_tab, asrc, adst);
    k_gatE    <<<N_NODES / 4, 256, 0, stream>>>(offs, se_csr, asrc, adst, h_tab, U_all);
    k_fuse    <<<(N_NODES + FBM - 1) / FBM, 256, 0, stream>>>(U_all, gat_lin, gat_bias,
                                                              fc_w, fc_b, y);
}

// Round 6
// 310.400 us; speedup vs baseline: 1.2373x; 1.0088x over previous
//
#include <hip/hip_runtime.h>

#define N_NODES 50000
#define N_EDGES 800000
#define IN_C 8
#define OUT_C 16
#define EDGE_F 8
#define HEADS 4
#define HID 64
#define GDIM (HEADS*HID)   // 256
#define FINAL 128
#define NEG_SLOPE 0.2f
#define EB ((N_EDGES+255)/256)      // 3125
#define NBLK 196                    // ceil(N_NODES/256)

__device__ __forceinline__ int clampn(int v) {
    return v < 0 ? 0 : (v >= N_NODES ? N_NODES - 1 : v);
}

// ---------- K_histfold: dst histogram + rank, plus folded attention weights ----------
__global__ __launch_bounds__(256) void k_histfold(
    const int* __restrict__ dst, int* __restrict__ cnt, int* __restrict__ rnk,
    const float* __restrict__ gat_lin,
    const float* __restrict__ att_src_w, const float* __restrict__ att_dst_w,
    float* __restrict__ wsrc, float* __restrict__ wdst)
{
    if (blockIdx.x < EB) {
        int e = blockIdx.x * 256 + threadIdx.x;
        if (e >= N_EDGES) return;
        rnk[e] = atomicAdd(&cnt[clampn(dst[e])], 1);
    } else {
        int t = threadIdx.x;           // t = c*4 + h
        if (t >= 64) return;
        int c = t >> 2, h = t & 3;
        float ws = 0.f, wd = 0.f;
        for (int k = 0; k < HID; k++) {
            float l = gat_lin[c * GDIM + h * HID + k];
            ws += l * att_src_w[h * HID + k];
            wd += l * att_dst_w[h * HID + k];
        }
        wsrc[t] = ws;
        wdst[t] = wd;
    }
}

// ---------- scan pipeline ----------
__global__ __launch_bounds__(256) void k_part(const int* __restrict__ cnt,
                                              int* __restrict__ part)
{
    int i = blockIdx.x * 256 + threadIdx.x;
    int v = (i < N_NODES) ? cnt[i] : 0;
#pragma unroll
    for (int off = 32; off; off >>= 1) v += __shfl_down(v, off);
    __shared__ int ws[4];
    if ((threadIdx.x & 63) == 0) ws[threadIdx.x >> 6] = v;
    __syncthreads();
    if (threadIdx.x == 0) part[blockIdx.x] = ws[0] + ws[1] + ws[2] + ws[3];
}

__global__ __launch_bounds__(256) void k_scan1(const int* __restrict__ part,
                                               int* __restrict__ partscan)
{
    int t = threadIdx.x;
    int v = (t < NBLK) ? part[t] : 0;
    int lane = t & 63, wid = t >> 6;
    int incl = v;
#pragma unroll
    for (int off = 1; off < 64; off <<= 1) {
        int u = __shfl_up(incl, off);
        if (lane >= off) incl += u;
    }
    __shared__ int wsum[4];
    if (lane == 63) wsum[wid] = incl;
    __syncthreads();
    int add = 0;
    for (int w = 0; w < wid; w++) add += wsum[w];
    partscan[t] = incl - v + add;   // exclusive
}

__global__ __launch_bounds__(256) void k_add(const int* __restrict__ cnt,
                                             const int* __restrict__ partscan,
                                             int* __restrict__ offs)
{
    int i = blockIdx.x * 256 + threadIdx.x;
    int v = (i < N_NODES) ? cnt[i] : 0;
    int lane = threadIdx.x & 63, wid = threadIdx.x >> 6;
    int incl = v;
#pragma unroll
    for (int off = 1; off < 64; off <<= 1) {
        int u = __shfl_up(incl, off);
        if (lane >= off) incl += u;
    }
    __shared__ int wsum[4];
    if (lane == 63) wsum[wid] = incl;
    __syncthreads();
    int add = partscan[blockIdx.x];
    for (int w = 0; w < wid; w++) add += wsum[w];
    if (i < N_NODES) offs[i] = incl - v + add;
    if (i == 0) offs[N_NODES] = N_EDGES;
}

__global__ __launch_bounds__(256) void k_scatter(
    const int* __restrict__ src, const int* __restrict__ dst,
    const int* __restrict__ rnk, const int* __restrict__ offs,
    int2* __restrict__ se_csr)
{
    int e = blockIdx.x * 256 + threadIdx.x;
    if (e >= N_EDGES) return;
    int p = offs[clampn(dst[e])] + rnk[e];
    se_csr[p] = make_int2(clampn(src[e]), e);
}

// ---------- K2T: wave-per-node T-factorized NNConv, software-pipelined gathers ----
// T[d,f,i] = sum_{e->d} ea[e,f]*x[s_e,i]; h = relu(W.T + b.xs + x@root + bias)
// Pipeline: chunk n's operands in regs; iteration n issues chunk n+1's index
// loads + gathers BEFORE consuming chunk n -> gather latency overlaps compute
// and next-issue. Arithmetic order identical to the non-pipelined version.
__global__ __launch_bounds__(256) void k2T_wave(
    const float* __restrict__ x,
    const int2* __restrict__ se_csr, const int* __restrict__ offs,
    const float* __restrict__ ea,
    const float* __restrict__ mlp_w, const float* __restrict__ mlp_b,
    const float* __restrict__ ecc_root, const float* __restrict__ ecc_bias,
    const float* __restrict__ wsrc, const float* __restrict__ wdst,
    float* __restrict__ h_tab, float* __restrict__ asrc, float* __restrict__ adst)
{
    __shared__ float smW[64 * 17];   // [jj][o] pitch-17 (bank-friendly)
    __shared__ float smb[128];
    __shared__ float sroot[128];
    __shared__ float sbias[16];
    __shared__ float sws[64], swd[64];
    __shared__ float sT[4][64];
    __shared__ float sxs[4][8];

    int t = threadIdx.x;
    for (int idx = t; idx < 1024; idx += 256)
        smW[(idx >> 4) * 17 + (idx & 15)] = mlp_w[idx];
    if (t < 128) smb[t] = mlp_b[t];
    if (t >= 128 && t < 256) sroot[t - 128] = ecc_root[t - 128];
    if (t < 16) sbias[t] = ecc_bias[t];
    if (t >= 32 && t < 96) sws[t - 32] = wsrc[t - 32];
    if (t >= 96 && t < 160) swd[t - 96] = wdst[t - 96];

    int wid = t >> 6, lane = t & 63;
    int n = blockIdx.x * 4 + wid;   // grid = 12500 exactly
    int f = lane >> 3, i = lane & 7;
    int beg = offs[n], end = offs[n + 1];

    float t0 = 0.f, t1 = 0.f, t2 = 0.f, t3 = 0.f, xs = 0.f;
    int j = beg;
    if (j + 3 < end) {
        // prologue: load + gather chunk 0
        int2 se0 = se_csr[j],     se1 = se_csr[j + 1];
        int2 se2 = se_csr[j + 2], se3 = se_csr[j + 3];
        float a0 = ea[(unsigned)se0.y * EDGE_F + f];
        float a1 = ea[(unsigned)se1.y * EDGE_F + f];
        float a2 = ea[(unsigned)se2.y * EDGE_F + f];
        float a3 = ea[(unsigned)se3.y * EDGE_F + f];
        float x0 = x[(unsigned)se0.x * IN_C + i];
        float x1 = x[(unsigned)se1.x * IN_C + i];
        float x2 = x[(unsigned)se2.x * IN_C + i];
        float x3 = x[(unsigned)se3.x * IN_C + i];
        j += 4;
        for (; j + 3 < end; j += 4) {
            // issue chunk n+1 loads first
            int2 ne0 = se_csr[j],     ne1 = se_csr[j + 1];
            int2 ne2 = se_csr[j + 2], ne3 = se_csr[j + 3];
            float na0 = ea[(unsigned)ne0.y * EDGE_F + f];
            float na1 = ea[(unsigned)ne1.y * EDGE_F + f];
            float na2 = ea[(unsigned)ne2.y * EDGE_F + f];
            float na3 = ea[(unsigned)ne3.y * EDGE_F + f];
            float nx0 = x[(unsigned)ne0.x * IN_C + i];
            float nx1 = x[(unsigned)ne1.x * IN_C + i];
            float nx2 = x[(unsigned)ne2.x * IN_C + i];
            float nx3 = x[(unsigned)ne3.x * IN_C + i];
            // consume chunk n
            t0 += a0 * x0; t1 += a1 * x1; t2 += a2 * x2; t3 += a3 * x3;
            xs += (x0 + x1) + (x2 + x3);
            // rotate
            a0 = na0; a1 = na1; a2 = na2; a3 = na3;
            x0 = nx0; x1 = nx1; x2 = nx2; x3 = nx3;
        }
        // drain
        t0 += a0 * x0; t1 += a1 * x1; t2 += a2 * x2; t3 += a3 * x3;
        xs += (x0 + x1) + (x2 + x3);
    }
    for (; j < end; j++) {
        int2 se = se_csr[j];
        float a = ea[(unsigned)se.y * EDGE_F + f];
        float xv = x[(unsigned)se.x * IN_C + i];
        t0 += a * xv;
        xs += xv;
    }
    sT[wid][lane] = (t0 + t1) + (t2 + t3);
    if (f == 0) sxs[wid][i] = xs;
    __syncthreads();     // covers LDS preloads + sT/sxs

    // p-parallel 64x16 contraction: lane = p*16 + o, partial over jj=p*16..+15
    int o = lane & 15, p = lane >> 4;
    float v = 0.f;
#pragma unroll
    for (int q2 = 0; q2 < 16; q2++) {
        int jj = p * 16 + q2;
        v += smW[jj * 17 + o] * sT[wid][jj];
    }
    v += __shfl_down(v, 32);
    v += __shfl_down(v, 16);    // lanes<16 hold full sums

    float hv = 0.f;
    if (lane < 16) {
        float vv = v + sbias[o];
#pragma unroll
        for (int ii = 0; ii < IN_C; ii++) {
            vv += smb[ii * 16 + o] * sxs[wid][ii];
            vv += x[n * IN_C + ii] * sroot[ii * 16 + o];
        }
        hv = fmaxf(vv, 0.f);
        h_tab[n * OUT_C + o] = hv;
    }
    // folded attention logits
    float as = 0.f, ad = 0.f;
    int h2 = lane & 3;
#pragma unroll
    for (int c = 0; c < 16; c++) {
        float hc = __shfl(hv, c);
        as += hc * sws[c * 4 + h2];
        ad += hc * swd[c * 4 + h2];
    }
    if (lane < 4) {
        asrc[n * HEADS + lane] = as;
        adst[n * HEADS + lane] = ad;
    }
}

// ---------- K_gatE: wave-per-node U accumulation, software-pipelined ----------
// lane = h*16+c; den is identical across the 16 lanes of a head -> no reduce.
__global__ __launch_bounds__(256) void k_gatE(
    const int* __restrict__ offs, const int2* __restrict__ se_csr,
    const float* __restrict__ asrc, const float* __restrict__ adst,
    const float* __restrict__ h_tab, float* __restrict__ U_all)
{
    int t = threadIdx.x;
    int wid = t >> 6, lane = t & 63;
    int n = blockIdx.x * 4 + wid;   // grid = 12500 exactly
    int h = lane >> 4, c = lane & 15;
    float adsth = adst[n * HEADS + h];
    int beg = offs[n], end = offs[n + 1];

    float U = 0.f, den = 0.f;
    int j = beg;
    if (j + 3 < end) {
        int s0 = se_csr[j].x,     s1 = se_csr[j + 1].x;
        int s2 = se_csr[j + 2].x, s3 = se_csr[j + 3].x;
        float av0 = asrc[(unsigned)s0 * HEADS + h], av1 = asrc[(unsigned)s1 * HEADS + h];
        float av2 = asrc[(unsigned)s2 * HEADS + h], av3 = asrc[(unsigned)s3 * HEADS + h];
        float h0 = h_tab[(unsigned)s0 * OUT_C + c], h1 = h_tab[(unsigned)s1 * OUT_C + c];
        float h2v = h_tab[(unsigned)s2 * OUT_C + c], h3v = h_tab[(unsigned)s3 * OUT_C + c];
        j += 4;
        for (; j + 3 < end; j += 4) {
            int ns0 = se_csr[j].x,     ns1 = se_csr[j + 1].x;
            int ns2 = se_csr[j + 2].x, ns3 = se_csr[j + 3].x;
            float nav0 = asrc[(unsigned)ns0 * HEADS + h];
            float nav1 = asrc[(unsigned)ns1 * HEADS + h];
            float nav2 = asrc[(unsigned)ns2 * HEADS + h];
            float nav3 = asrc[(unsigned)ns3 * HEADS + h];
            float nh0 = h_tab[(unsigned)ns0 * OUT_C + c];
            float nh1 = h_tab[(unsigned)ns1 * OUT_C + c];
            float nh2 = h_tab[(unsigned)ns2 * OUT_C + c];
            float nh3 = h_tab[(unsigned)ns3 * OUT_C + c];
            float v0 = av0 + adsth; v0 = v0 > 0.f ? v0 : NEG_SLOPE * v0;
            float v1 = av1 + adsth; v1 = v1 > 0.f ? v1 : NEG_SLOPE * v1;
            float v2 = av2 + adsth; v2 = v2 > 0.f ? v2 : NEG_SLOPE * v2;
            float v3 = av3 + adsth; v3 = v3 > 0.f ? v3 : NEG_SLOPE * v3;
            float p0 = __expf(v0), p1 = __expf(v1), p2 = __expf(v2), p3 = __expf(v3);
            den += (p0 + p1) + (p2 + p3);
            U += p0 * h0 + p1 * h1 + p2 * h2v + p3 * h3v;
            av0 = nav0; av1 = nav1; av2 = nav2; av3 = nav3;
            h0 = nh0; h1 = nh1; h2v = nh2; h3v = nh3;
        }
        float v0 = av0 + adsth; v0 = v0 > 0.f ? v0 : NEG_SLOPE * v0;
        float v1 = av1 + adsth; v1 = v1 > 0.f ? v1 : NEG_SLOPE * v1;
        float v2 = av2 + adsth; v2 = v2 > 0.f ? v2 : NEG_SLOPE * v2;
        float v3 = av3 + adsth; v3 = v3 > 0.f ? v3 : NEG_SLOPE * v3;
        float p0 = __expf(v0), p1 = __expf(v1), p2 = __expf(v2), p3 = __expf(v3);
        den += (p0 + p1) + (p2 + p3);
        U += p0 * h0 + p1 * h1 + p2 * h2v + p3 * h3v;
    }
    for (; j < end; j++) {
        int s = se_csr[j].x;
        float av = asrc[(unsigned)s * HEADS + h];
        float hvv = h_tab[(unsigned)s * OUT_C + c];
        float v = av + adsth; v = v > 0.f ? v : NEG_SLOPE * v;
        float pe = __expf(v);
        den += pe;
        U += pe * hvv;
    }
    U_all[(size_t)n * 64 + lane] = U / (den + 1e-16f);
}

// ---------- K_fuse v5: 256 thr, FBM=64, 4x8 thread tile, split columns ----------
// y = relu( (Unorm @ blockdiag(gat_lin)) + gat_bias ) @ fc_w + fc_b
// Per kk: 3 ds_read_b128 per 32 FMA. Column split {cg*4, cg*4+64} keeps every
// b128 read/store at 16B stride across the wave -> all 32 banks, 2-way (free).
// LDS 28.4 KB; grid 782.
#define FBM 64
__global__ __launch_bounds__(256) void k_fuse(
    const float* __restrict__ U_all, const float* __restrict__ gat_lin,
    const float* __restrict__ gat_bias, const float* __restrict__ fc_w,
    const float* __restrict__ fc_b, float* __restrict__ y)
{
    __shared__ float slin[16 * GDIM];     // 16 KB (whole gat_lin [16][256])
    __shared__ float sA[16][FBM + 4];     // 4.35 KB, pitch 68
    __shared__ float sW[16][FINAL];       // 8 KB
    int tid = threadIdx.x;
    int r0 = blockIdx.x * FBM;

    for (int idx = tid; idx < (16 * GDIM) / 4; idx += 256)
        ((float4*)slin)[idx] = ((const float4*)gat_lin)[idx];
    __syncthreads();    // slin visible before first G-gen

    // G-gen mapping: 64 rows x 4 col-quads
    int ar  = tid >> 2;          // 0..63  row within tile
    int akq = (tid & 3) * 4;     // 0,4,8,12: col quad within 16-wide k-tile
    int grow = r0 + ar;

    // mm mapping: 4 rows x 8 cols (split halves) per thread
    int rg = tid >> 4;           // 0..15 -> rows rg*4..+3
    int cg = tid & 15;           // cols cg*4..+3 and cg*4+64..+67

    // sW staging: 16 rows x (16 quads x 2 halves)
    int skk = tid >> 4;          // 0..15
    int scc = (tid & 15) * 4;    // 0,4,..,60

    float acc[4][8];
#pragma unroll
    for (int r = 0; r < 4; r++)
#pragma unroll
        for (int c = 0; c < 8; c++) acc[r][c] = 0.f;

    for (int h = 0; h < HEADS; ++h) {
        // this thread's U row slice for head h, kept in registers
        float4 ua = make_float4(0.f, 0.f, 0.f, 0.f), ub = ua, uc4 = ua, ud = ua;
        if (grow < N_NODES) {
            const float4* up = (const float4*)&U_all[(size_t)grow * 64 + h * 16];
            ua = up[0]; ub = up[1]; uc4 = up[2]; ud = up[3];
        }
        float ureg[16] = {ua.x, ua.y, ua.z, ua.w,  ub.x, ub.y, ub.z, ub.w,
                          uc4.x, uc4.y, uc4.z, uc4.w,  ud.x, ud.y, ud.z, ud.w};

#pragma unroll
        for (int tt = 0; tt < 4; ++tt) {
            int k0 = h * 64 + tt * 16;
            float4 bv = *(const float4*)&gat_bias[k0 + akq];
            float g0 = 0.f, g1 = 0.f, g2 = 0.f, g3 = 0.f;
#pragma unroll
            for (int c = 0; c < 16; ++c) {
                float4 lv = *(const float4*)&slin[c * GDIM + k0 + akq];
                g0 += ureg[c] * lv.x;
                g1 += ureg[c] * lv.y;
                g2 += ureg[c] * lv.z;
                g3 += ureg[c] * lv.w;
            }
            __syncthreads();   // previous tile's mm reads complete
            sA[akq + 0][ar] = fmaxf(g0 + bv.x, 0.f);
            sA[akq + 1][ar] = fmaxf(g1 + bv.y, 0.f);
            sA[akq + 2][ar] = fmaxf(g2 + bv.z, 0.f);
            sA[akq + 3][ar] = fmaxf(g3 + bv.w, 0.f);
            {
                const float* wrow = &fc_w[(size_t)(k0 + skk) * FINAL];
                *(float4*)&sW[skk][scc]      = *(const float4*)&wrow[scc];
                *(float4*)&sW[skk][scc + 64] = *(const float4*)&wrow[scc + 64];
            }
            __syncthreads();   // sA/sW ready
#pragma unroll
            for (int kk = 0; kk < 16; ++kk) {
                float4 a  = *(const float4*)&sA[kk][rg * 4];
                float4 w0 = *(const float4*)&sW[kk][cg * 4];
                float4 w1 = *(const float4*)&sW[kk][cg * 4 + 64];
                float av[4] = {a.x, a.y, a.z, a.w};
#pragma unroll
                for (int r = 0; r < 4; r++) {
                    acc[r][0] += av[r] * w0.x;
                    acc[r][1] += av[r] * w0.y;
                    acc[r][2] += av[r] * w0.z;
                    acc[r][3] += av[r] * w0.w;
                    acc[r][4] += av[r] * w1.x;
                    acc[r][5] += av[r] * w1.y;
                    acc[r][6] += av[r] * w1.z;
                    acc[r][7] += av[r] * w1.w;
                }
            }
        }
    }

    float4 fb0 = *(const float4*)&fc_b[cg * 4];
    float4 fb1 = *(const float4*)&fc_b[cg * 4 + 64];
#pragma unroll
    for (int r = 0; r < 4; r++) {
        int row = r0 + rg * 4 + r;
        if (row < N_NODES) {
            float* yp = &y[(size_t)row * FINAL];
            *(float4*)&yp[cg * 4] =
                make_float4(acc[r][0] + fb0.x, acc[r][1] + fb0.y,
                            acc[r][2] + fb0.z, acc[r][3] + fb0.w);
            *(float4*)&yp[cg * 4 + 64] =
                make_float4(acc[r][4] + fb1.x, acc[r][5] + fb1.y,
                            acc[r][6] + fb1.z, acc[r][7] + fb1.w);
        }
    }
}

extern "C" void kernel_launch(void* const* d_in, const int* in_sizes, int n_in,
                              void* d_out, int out_size, void* d_ws, size_t ws_size,
                              hipStream_t stream)
{
    const float* x        = (const float*)d_in[0];
    const int*   ei       = (const int*)d_in[1];
    const float* ea       = (const float*)d_in[2];
    const float* ecc_root = (const float*)d_in[3];
    const float* ecc_bias = (const float*)d_in[4];
    const float* mlp_w    = (const float*)d_in[5];
    const float* mlp_b    = (const float*)d_in[6];
    const float* gat_lin  = (const float*)d_in[7];
    const float* att_src  = (const float*)d_in[8];
    const float* att_dst  = (const float*)d_in[9];
    const float* gat_bias = (const float*)d_in[10];
    const float* fc_w     = (const float*)d_in[11];
    const float* fc_b     = (const float*)d_in[12];
    float* y = (float*)d_out;

    const int* src = ei;
    const int* dst = ei + N_EDGES;

    // workspace layout
    float* h_tab = (float*)d_ws;                                  // N*16  (3.2 MB)
    float* U_all = h_tab + (size_t)N_NODES * OUT_C;               // N*64  (12.8 MB)
    float* asrc  = U_all + (size_t)N_NODES * 64;                  // N*4
    float* adst  = asrc + (size_t)N_NODES * HEADS;                // N*4
    float* wsrc  = adst + (size_t)N_NODES * HEADS;                // 64
    float* wdst  = wsrc + 64;                                     // 64
    int*   cnt      = (int*)(wdst + 64);                          // N
    int*   offs     = cnt + N_NODES;                              // N+1
    int*   part     = offs + N_NODES + 1;                         // 256
    int*   partscan = part + 256;                                 // 256
    int*   rnk      = partscan + 256;                             // E
    int2*  se_csr   = (int2*)(rnk + N_EDGES + 1);                 // E int2 (8B-aligned)

    hipMemsetAsync(cnt, 0, sizeof(int) * N_NODES, stream);

    k_histfold<<<EB + 1, 256, 0, stream>>>(dst, cnt, rnk, gat_lin, att_src, att_dst,
                                           wsrc, wdst);
    k_part    <<<NBLK, 256, 0, stream>>>(cnt, part);
    k_scan1   <<<1, 256, 0, stream>>>(part, partscan);
    k_add     <<<NBLK, 256, 0, stream>>>(cnt, partscan, offs);
    k_scatter <<<EB, 256, 0, stream>>>(src, dst, rnk, offs, se_csr);

    k2T_wave  <<<N_NODES / 4, 256, 0, stream>>>(x, se_csr, offs, ea, mlp_w, mlp_b,
                                                ecc_root, ecc_bias, wsrc, wdst,
                                                h_tab, asrc, adst);
    k_gatE    <<<N_NODES / 4, 256, 0, stream>>>(offs, se_csr, asrc, adst, h_tab, U_all);
    k_fuse    <<<(N_NODES + FBM - 1) / FBM, 256, 0, stream>>>(U_all, gat_lin, gat_bias,
                                                              fc_w, fc_b, y);
}